// Round 2
// baseline (549.911 us; speedup 1.0000x reference)
//
#include <hip/hip_runtime.h>
#include <hip/hip_bf16.h>

#define BATCH 32768
#define IN_DIM 64
#define NUM_CLASSES 4096

typedef short bf16x8 __attribute__((ext_vector_type(8)));   // 8 bf16 = 4 VGPRs
typedef float f32x4 __attribute__((ext_vector_type(4)));    // MFMA 16x16 accumulator

// Convert fp32 rows (length 64) to bf16 and emit per-row sum of squares (fp32).
// One float4 (4 elements) per thread; a row = 16 consecutive threads.
__global__ void convert_rows(const float* __restrict__ src,
                             unsigned short* __restrict__ dst,
                             float* __restrict__ sq) {
    int t = blockIdx.x * blockDim.x + threadIdx.x;
    float4 v = ((const float4*)src)[t];

    __hip_bfloat16 h0 = __float2bfloat16(v.x);
    __hip_bfloat16 h1 = __float2bfloat16(v.y);
    __hip_bfloat16 h2 = __float2bfloat16(v.z);
    __hip_bfloat16 h3 = __float2bfloat16(v.w);
    ushort4 o;
    o.x = __builtin_bit_cast(unsigned short, h0);
    o.y = __builtin_bit_cast(unsigned short, h1);
    o.z = __builtin_bit_cast(unsigned short, h2);
    o.w = __builtin_bit_cast(unsigned short, h3);
    ((ushort4*)dst)[t] = o;

    float s = v.x * v.x + v.y * v.y + v.z * v.z + v.w * v.w;
    s += __shfl_xor(s, 1, 16);
    s += __shfl_xor(s, 2, 16);
    s += __shfl_xor(s, 4, 16);
    s += __shfl_xor(s, 8, 16);
    if ((threadIdx.x & 15) == 0) sq[t >> 4] = s;
}

// logits[m][n] = 2*dot(x[m], w[n]) - xsq[m] - 64   (||w||^2 == 64 exactly: w in {+-1}^64)
//
// Block tile: 32 rows x FULL 4096 cols -> each block writes one CONTIGUOUS
// 512-KiB region of out (DRAM-page-friendly streaming, mimicking the 6.3 TB/s
// fill pattern). 1024 blocks, 4 waves each.
//
// Column sweep: 64 chunks of 64 cols; at step t, wave w handles chunk c = t*4+w,
// so the 4 waves write ADJACENT 256-B runs -> block front = 32 rows x 1 KiB,
// advancing sequentially through each 16-KiB output row.
//
// MFMA operands SWAPPED (mfma(b, a, acc)): acc[i][j][e] =
//   cross[m0 + i*16 + r][c*64 + j*16 + quad*4 + e]
// so each thread owns 4 contiguous floats of one output row.
//
// Epilogue: wave-PRIVATE 8-KiB swizzled LDS transpose (no barriers needed;
// same-wave DS ops are ordered) -> global stores are 4 rows x 256-B runs.
__global__ __launch_bounds__(256) void rbf_gemm(
    const unsigned short* __restrict__ xb,   // [BATCH][64] bf16
    const unsigned short* __restrict__ wb,   // [NUM_CLASSES][64] bf16
    const float* __restrict__ xsq,           // [BATCH]
    float* __restrict__ out)                 // [BATCH][NUM_CLASSES]
{
    __shared__ float lds[4 * 2048];          // 4 waves x 8 KiB (32 rows x 256 B)

    const int lane = threadIdx.x & 63;
    const int wave = threadIdx.x >> 6;
    const int r    = lane & 15;
    const int quad = lane >> 4;
    const int m0   = blockIdx.x * 32;

    // A fragments: x rows m0 + i*16 + r, k-chunk quad*8 + s*32 (loaded once).
    const unsigned short* arow = xb + (size_t)(m0 + r) * IN_DIM + quad * 8;
    bf16x8 a[2][2];
#pragma unroll
    for (int i = 0; i < 2; ++i)
#pragma unroll
        for (int s = 0; s < 2; ++s)
            a[i][s] = *(const bf16x8*)(arow + i * 16 * IN_DIM + s * 32);

    float xs[2];
#pragma unroll
    for (int i = 0; i < 2; ++i) xs[i] = xsq[m0 + i * 16 + r];

    char* my = (char*)(lds + wave * 2048);   // wave-private transpose buffer

    // Register double-buffer for B fragments (statically indexed after unroll).
    bf16x8 b[2][4][2];
    {
        const int nbase = wave * 64;         // t = 0 chunk for this wave
        const unsigned short* brow = wb + (size_t)(nbase + r) * IN_DIM + quad * 8;
#pragma unroll
        for (int j = 0; j < 4; ++j)
#pragma unroll
            for (int s = 0; s < 2; ++s)
                b[0][j][s] = *(const bf16x8*)(brow + j * 16 * IN_DIM + s * 32);
    }

#pragma unroll
    for (int t = 0; t < 16; ++t) {
        const int cur = t & 1;

        // Prefetch next chunk's B fragments (1 iteration ahead).
        if (t < 15) {
            const int nbase = ((t + 1) * 4 + wave) * 64;
            const unsigned short* brow = wb + (size_t)(nbase + r) * IN_DIM + quad * 8;
#pragma unroll
            for (int j = 0; j < 4; ++j)
#pragma unroll
                for (int s = 0; s < 2; ++s)
                    b[cur ^ 1][j][s] = *(const bf16x8*)(brow + j * 16 * IN_DIM + s * 32);
        }

        f32x4 acc[2][4];
#pragma unroll
        for (int i = 0; i < 2; ++i)
#pragma unroll
            for (int j = 0; j < 4; ++j)
                acc[i][j] = (f32x4)0.0f;

#pragma unroll
        for (int s = 0; s < 2; ++s)
#pragma unroll
            for (int i = 0; i < 2; ++i)
#pragma unroll
                for (int j = 0; j < 4; ++j)
                    acc[i][j] = __builtin_amdgcn_mfma_f32_16x16x32_bf16(
                        b[cur][j][s], a[i][s], acc[i][j], 0, 0, 0);

        const int nbase = (t * 4 + wave) * 64;

        // ---- finished logits -> swizzled wave-private LDS ----
#pragma unroll
        for (int i = 0; i < 2; ++i) {
            const int rl  = i * 16 + r;                  // local row 0..31
            const int swz = (rl & 7) << 4;               // 16-B slot XOR
#pragma unroll
            for (int j = 0; j < 4; ++j) {
                f32x4 v;
                v[0] = 2.0f * acc[i][j][0] - xs[i] - 64.0f;
                v[1] = 2.0f * acc[i][j][1] - xs[i] - 64.0f;
                v[2] = 2.0f * acc[i][j][2] - xs[i] - 64.0f;
                v[3] = 2.0f * acc[i][j][3] - xs[i] - 64.0f;
                const int byte = rl * 256 + ((((j * 4 + quad) * 16)) ^ swz);
                *(f32x4*)(my + byte) = v;
            }
        }
        // No barrier: buffer is wave-private; same-wave DS ops stay ordered.

        // ---- row-major readback -> contiguous 256-B global runs ----
#pragma unroll
        for (int p = 0; p < 8; ++p) {
            const int rl  = p * 4 + quad;                // local row 0..31
            const int swz = (rl & 7) << 4;
            f32x4 v = *(const f32x4*)(my + rl * 256 + ((r * 16) ^ swz));
            *(f32x4*)(out + (size_t)(m0 + rl) * NUM_CLASSES + nbase + r * 4) = v;
        }
    }
}

extern "C" void kernel_launch(void* const* d_in, const int* in_sizes, int n_in,
                              void* d_out, int out_size, void* d_ws, size_t ws_size,
                              hipStream_t stream) {
    const float* x = (const float*)d_in[0];   // [32768, 64] fp32
    const float* w = (const float*)d_in[1];   // [4096, 64] fp32, values +/-1
    float* out = (float*)d_out;               // [32768, 4096] fp32

    // Workspace layout (~4.66 MiB total):
    char* ws = (char*)d_ws;
    unsigned short* xb = (unsigned short*)ws;                                   // 4 MiB
    unsigned short* wb = (unsigned short*)(ws + (size_t)BATCH * IN_DIM * 2);    // 512 KiB
    float* xsq = (float*)(ws + (size_t)BATCH * IN_DIM * 2
                             + (size_t)NUM_CLASSES * IN_DIM * 2);               // 128 KiB
    float* wsq = xsq + BATCH;                                                   // 16 KiB (unused by gemm: ||w||^2==64)

    convert_rows<<<(BATCH * IN_DIM / 4) / 256, 256, 0, stream>>>(x, xb, xsq);
    convert_rows<<<(NUM_CLASSES * IN_DIM / 4) / 256, 256, 0, stream>>>(w, wb, wsq);

    const int grid = BATCH / 32;              // 1024 blocks, contiguous 512-KiB regions
    rbf_gemm<<<grid, 256, 0, stream>>>(xb, wb, xsq, out);
}

// Round 3
// 544.913 us; speedup vs baseline: 1.0092x; 1.0092x over previous
//
#include <hip/hip_runtime.h>
#include <hip/hip_bf16.h>

#define BATCH 32768
#define IN_DIM 64
#define NUM_CLASSES 4096

typedef short bf16x8 __attribute__((ext_vector_type(8)));   // 8 bf16 = 4 VGPRs
typedef float f32x4 __attribute__((ext_vector_type(4)));    // MFMA 16x16 accumulator

// Convert fp32 rows (length 64) to bf16 and emit per-row sum of squares (fp32).
// One float4 (4 elements) per thread; a row = 16 consecutive threads.
__global__ void convert_rows(const float* __restrict__ src,
                             unsigned short* __restrict__ dst,
                             float* __restrict__ sq) {
    int t = blockIdx.x * blockDim.x + threadIdx.x;
    float4 v = ((const float4*)src)[t];

    __hip_bfloat16 h0 = __float2bfloat16(v.x);
    __hip_bfloat16 h1 = __float2bfloat16(v.y);
    __hip_bfloat16 h2 = __float2bfloat16(v.z);
    __hip_bfloat16 h3 = __float2bfloat16(v.w);
    ushort4 o;
    o.x = __builtin_bit_cast(unsigned short, h0);
    o.y = __builtin_bit_cast(unsigned short, h1);
    o.z = __builtin_bit_cast(unsigned short, h2);
    o.w = __builtin_bit_cast(unsigned short, h3);
    ((ushort4*)dst)[t] = o;

    float s = v.x * v.x + v.y * v.y + v.z * v.z + v.w * v.w;
    s += __shfl_xor(s, 1, 16);
    s += __shfl_xor(s, 2, 16);
    s += __shfl_xor(s, 4, 16);
    s += __shfl_xor(s, 8, 16);
    if ((threadIdx.x & 15) == 0) sq[t >> 4] = s;
}

// logits[m][n] = 2*dot(x[m], w[n]) - xsq[m] - 64   (||w||^2 == 64 exactly: w in {+-1}^64)
//
// Block tile: 32 rows x FULL 4096 cols -> each block writes one CONTIGUOUS
// 512-KiB region of out. 1024 blocks, 4 waves each.
//
// Round-3 single-variable change: output stores are NONTEMPORAL (no-allocate).
// Theory: default stores read-allocate in L2, fetching every output line from
// HBM before overwrite -> 2x HBM traffic on a pure write stream. `nt` stores
// take the same no-allocate path the 6.3 TB/s fill uses (fill: WRITE=2 GiB,
// FETCH=14 KB).
__global__ __launch_bounds__(256) void rbf_gemm(
    const unsigned short* __restrict__ xb,   // [BATCH][64] bf16
    const unsigned short* __restrict__ wb,   // [NUM_CLASSES][64] bf16
    const float* __restrict__ xsq,           // [BATCH]
    float* __restrict__ out)                 // [BATCH][NUM_CLASSES]
{
    __shared__ float lds[4 * 2048];          // 4 waves x 8 KiB (32 rows x 256 B)

    const int lane = threadIdx.x & 63;
    const int wave = threadIdx.x >> 6;
    const int r    = lane & 15;
    const int quad = lane >> 4;
    const int m0   = blockIdx.x * 32;

    // A fragments: x rows m0 + i*16 + r, k-chunk quad*8 + s*32 (loaded once).
    const unsigned short* arow = xb + (size_t)(m0 + r) * IN_DIM + quad * 8;
    bf16x8 a[2][2];
#pragma unroll
    for (int i = 0; i < 2; ++i)
#pragma unroll
        for (int s = 0; s < 2; ++s)
            a[i][s] = *(const bf16x8*)(arow + i * 16 * IN_DIM + s * 32);

    float xs[2];
#pragma unroll
    for (int i = 0; i < 2; ++i) xs[i] = xsq[m0 + i * 16 + r];

    char* my = (char*)(lds + wave * 2048);   // wave-private transpose buffer

    // Register double-buffer for B fragments (statically indexed after unroll).
    bf16x8 b[2][4][2];
    {
        const int nbase = wave * 64;         // t = 0 chunk for this wave
        const unsigned short* brow = wb + (size_t)(nbase + r) * IN_DIM + quad * 8;
#pragma unroll
        for (int j = 0; j < 4; ++j)
#pragma unroll
            for (int s = 0; s < 2; ++s)
                b[0][j][s] = *(const bf16x8*)(brow + j * 16 * IN_DIM + s * 32);
    }

#pragma unroll
    for (int t = 0; t < 16; ++t) {
        const int cur = t & 1;

        // Prefetch next chunk's B fragments (1 iteration ahead).
        if (t < 15) {
            const int nbase = ((t + 1) * 4 + wave) * 64;
            const unsigned short* brow = wb + (size_t)(nbase + r) * IN_DIM + quad * 8;
#pragma unroll
            for (int j = 0; j < 4; ++j)
#pragma unroll
                for (int s = 0; s < 2; ++s)
                    b[cur ^ 1][j][s] = *(const bf16x8*)(brow + j * 16 * IN_DIM + s * 32);
        }

        f32x4 acc[2][4];
#pragma unroll
        for (int i = 0; i < 2; ++i)
#pragma unroll
            for (int j = 0; j < 4; ++j)
                acc[i][j] = (f32x4)0.0f;

#pragma unroll
        for (int s = 0; s < 2; ++s)
#pragma unroll
            for (int i = 0; i < 2; ++i)
#pragma unroll
                for (int j = 0; j < 4; ++j)
                    acc[i][j] = __builtin_amdgcn_mfma_f32_16x16x32_bf16(
                        b[cur][j][s], a[i][s], acc[i][j], 0, 0, 0);

        const int nbase = (t * 4 + wave) * 64;

        // ---- finished logits -> swizzled wave-private LDS ----
#pragma unroll
        for (int i = 0; i < 2; ++i) {
            const int rl  = i * 16 + r;                  // local row 0..31
            const int swz = (rl & 7) << 4;               // 16-B slot XOR
#pragma unroll
            for (int j = 0; j < 4; ++j) {
                f32x4 v;
                v[0] = 2.0f * acc[i][j][0] - xs[i] - 64.0f;
                v[1] = 2.0f * acc[i][j][1] - xs[i] - 64.0f;
                v[2] = 2.0f * acc[i][j][2] - xs[i] - 64.0f;
                v[3] = 2.0f * acc[i][j][3] - xs[i] - 64.0f;
                const int byte = rl * 256 + ((((j * 4 + quad) * 16)) ^ swz);
                *(f32x4*)(my + byte) = v;
            }
        }
        // No barrier: buffer is wave-private; same-wave DS ops stay ordered.

        // ---- row-major readback -> contiguous 256-B nontemporal global runs ----
#pragma unroll
        for (int p = 0; p < 8; ++p) {
            const int rl  = p * 4 + quad;                // local row 0..31
            const int swz = (rl & 7) << 4;
            f32x4 v = *(const f32x4*)(my + rl * 256 + ((r * 16) ^ swz));
            __builtin_nontemporal_store(
                v, (f32x4*)(out + (size_t)(m0 + rl) * NUM_CLASSES + nbase + r * 4));
        }
    }
}

extern "C" void kernel_launch(void* const* d_in, const int* in_sizes, int n_in,
                              void* d_out, int out_size, void* d_ws, size_t ws_size,
                              hipStream_t stream) {
    const float* x = (const float*)d_in[0];   // [32768, 64] fp32
    const float* w = (const float*)d_in[1];   // [4096, 64] fp32, values +/-1
    float* out = (float*)d_out;               // [32768, 4096] fp32

    // Workspace layout (~4.66 MiB total):
    char* ws = (char*)d_ws;
    unsigned short* xb = (unsigned short*)ws;                                   // 4 MiB
    unsigned short* wb = (unsigned short*)(ws + (size_t)BATCH * IN_DIM * 2);    // 512 KiB
    float* xsq = (float*)(ws + (size_t)BATCH * IN_DIM * 2
                             + (size_t)NUM_CLASSES * IN_DIM * 2);               // 128 KiB
    float* wsq = xsq + BATCH;                                                   // 16 KiB (unused by gemm: ||w||^2==64)

    convert_rows<<<(BATCH * IN_DIM / 4) / 256, 256, 0, stream>>>(x, xb, xsq);
    convert_rows<<<(NUM_CLASSES * IN_DIM / 4) / 256, 256, 0, stream>>>(w, wb, wsq);

    const int grid = BATCH / 32;              // 1024 blocks, contiguous 512-KiB regions
    rbf_gemm<<<grid, 256, 0, stream>>>(xb, wb, xsq, out);
}